// Round 16
// baseline (235.529 us; speedup 1.0000x reference)
//
#include <hip/hip_runtime.h>
#include <stdint.h>

#define B_ 2
#define T_ 2048
#define DM 2048
#define NH 16
#define NKV 8
#define HD 128
#define NQKV 4096
#define SC2_ 0.12753102765f  // (1/sqrt(128)) * log2(e)

typedef float fx4 __attribute__((ext_vector_type(4)));
typedef __bf16 bfx8 __attribute__((ext_vector_type(8)));
typedef unsigned short u16;
typedef unsigned int u32;

typedef __attribute__((address_space(1))) const void gas_t;
typedef __attribute__((address_space(3))) void las_t;

__device__ __forceinline__ u16 f2bf(float f) {
  u32 u = __float_as_uint(f);
  u = (u + 0x7fffu + ((u >> 16) & 1u)) >> 16;
  return (u16)u;
}

// HW packed f32->bf16 pair (T12): lo -> bits[15:0], hi -> bits[31:16]
__device__ __forceinline__ u32 cvtpk(float lo, float hi) {
  u32 r;
  asm("v_cvt_pk_bf16_f32 %0, %1, %2" : "=v"(r) : "v"(lo), "v"(hi));
  return r;
}

// async global->LDS, 16B per lane; lds arg must be wave-uniform base + lane*16
__device__ __forceinline__ void stage16(const void* g, void* l) {
  __builtin_amdgcn_global_load_lds((gas_t*)(uintptr_t)g, (las_t*)(uintptr_t)l,
                                   16, 0, 0);
}

// ---------------- fp32 -> bf16 convert (x) ----------------
__global__ void k_cvt(const float* __restrict__ in, u16* __restrict__ out, int n) {
  int i = (blockIdx.x * blockDim.x + threadIdx.x) * 4;
  if (i + 3 < n) {
    float4 v = *(const float4*)(in + i);
    u32 w0 = (u32)f2bf(v.x) | ((u32)f2bf(v.y) << 16);
    u32 w1 = (u32)f2bf(v.z) | ((u32)f2bf(v.w) << 16);
    *(uint2*)(out + i) = make_uint2(w0, w1);
  }
}

// ---------------- fused weight convert: Wq|Wk|Wv|Wo -> contiguous bf16 ----------------
__global__ void k_cvtw(const float* __restrict__ wq, const float* __restrict__ wk,
                       const float* __restrict__ wv, const float* __restrict__ wo,
                       u16* __restrict__ out) {
  int i = (blockIdx.x * blockDim.x + threadIdx.x) * 4;
  const float* src;
  int off;
  if (i < 4194304) { src = wq; off = i; }
  else if (i < 6291456) { src = wk; off = i - 4194304; }
  else if (i < 8388608) { src = wv; off = i - 6291456; }
  else { src = wo; off = i - 8388608; }
  float4 v = *(const float4*)(src + off);
  u32 w0 = (u32)f2bf(v.x) | ((u32)f2bf(v.y) << 16);
  u32 w1 = (u32)f2bf(v.z) | ((u32)f2bf(v.w) << 16);
  *(uint2*)(out + i) = make_uint2(w0, w1);
}

// ======== QKV GEMM: 128x256 tile, BK=32 dbuf, grid 512 = 2 blocks/CU ========
// 256 thr / 4 waves; wave w owns 128x64 (acc[8][4]). Two independent blocks
// per CU overlap each other's barrier/stage drains (m114 mechanism).
// vmcnt ledger: stage = 6 ops/thread; steady vmcnt(6) drains tile-t; tail 0.
__global__ __launch_bounds__(256, 2) void k_gemm256(const u16* __restrict__ A,
                                                    const u16* __restrict__ Bm,
                                                    u16* __restrict__ C,
                                                    int M, int N, int K) {
  __shared__ __align__(16) u16 As[2][128 * 32];
  __shared__ __align__(16) u16 Bs[2][256 * 32];
  const int nbn = N >> 8;
  const int bm = blockIdx.x / nbn, bn = blockIdx.x % nbn;
  const int tid = threadIdx.x;
  const int w = tid >> 6, lane = tid & 63;
  const int lr = lane & 15, lg = lane >> 4;
  const int cw = (lg ^ ((lr >> 1) & 3)) * 8;
  const u16* Ab = A + (size_t)bm * 128 * K;
  const u16* Bb = Bm + (size_t)bn * 256 * K;
  const int NT = K >> 5;

  auto stage = [&](int buf, int tile) {
    u16* Ad = &As[buf][0];
    u16* Bd = &Bs[buf][0];
#pragma unroll
    for (int i = 0; i < 2; i++) {
      int q = tid + i * 256;
      int row = q >> 2, ch = q & 3;
      int sc = ch ^ ((row >> 1) & 3);
      stage16(Ab + (size_t)row * K + tile * 32 + sc * 8, Ad + q * 8);
    }
#pragma unroll
    for (int i = 0; i < 4; i++) {
      int q = tid + i * 256;
      int row = q >> 2, ch = q & 3;
      int sc = ch ^ ((row >> 1) & 3);
      stage16(Bb + (size_t)row * K + tile * 32 + sc * 8, Bd + q * 8);
    }
  };

  fx4 acc[8][4];
  const fx4 zero4 = {0.f, 0.f, 0.f, 0.f};
#pragma unroll
  for (int m = 0; m < 8; m++)
#pragma unroll
    for (int n = 0; n < 4; n++) acc[m][n] = zero4;

  stage(0, 0);
  asm volatile("s_waitcnt vmcnt(0)" ::: "memory");
  __builtin_amdgcn_s_barrier();

  const int arow = lr * 32;
  const int brow = (w * 64 + lr) * 32;
  bfx8 af[8], bf[4];

#pragma unroll 1
  for (int t = 0; t < NT; t++) {
    const int cur = t & 1;
    if (t + 1 < NT) {
      stage(cur ^ 1, t + 1);
      asm volatile("s_waitcnt vmcnt(6)" ::: "memory");
    } else {
      asm volatile("s_waitcnt vmcnt(0)" ::: "memory");  // tail drain (race fix)
    }
    __builtin_amdgcn_s_barrier();

    const u16* A0 = &As[cur][0];
    const u16* B0 = &Bs[cur][0];
#pragma unroll
    for (int mi = 0; mi < 8; mi++) af[mi] = *(const bfx8*)(A0 + arow + mi * 512 + cw);
#pragma unroll
    for (int n = 0; n < 4; n++) bf[n] = *(const bfx8*)(B0 + brow + n * 512 + cw);
    __builtin_amdgcn_s_setprio(1);
#pragma unroll
    for (int mi = 0; mi < 8; mi++)
#pragma unroll
      for (int n = 0; n < 4; n++)
        acc[mi][n] = __builtin_amdgcn_mfma_f32_16x16x32_bf16(af[mi], bf[n], acc[mi][n], 0, 0, 0);
    __builtin_amdgcn_s_setprio(0);
    __builtin_amdgcn_s_barrier();
  }

  const int r0 = bm * 128, c0 = bn * 256 + w * 64;
#pragma unroll
  for (int m = 0; m < 8; m++) {
#pragma unroll
    for (int n = 0; n < 4; n++) {
      int c = c0 + n * 16 + lr;
#pragma unroll
      for (int i = 0; i < 4; i++)
        C[(size_t)(r0 + m * 16 + lg * 4 + i) * N + c] = f2bf(acc[m][n][i]);
    }
  }
}

// ======== 128x128 GEMM, 2 merged phases/K-tile, f32+bias out (r15, PASSING) ========
__global__ __launch_bounds__(256, 2) void k_gemmo(const u16* __restrict__ A,
                                                  const u16* __restrict__ Bm,
                                                  float* __restrict__ C,
                                                  const float* __restrict__ bias,
                                                  int M, int N, int K) {
  __shared__ __align__(16) u16 As[2][2][128 * 32];
  __shared__ __align__(16) u16 Bs[2][2][128 * 32];
  const int nbn = N >> 7;
  const int bm = blockIdx.x / nbn, bn = blockIdx.x % nbn;
  const int tid = threadIdx.x;
  const int w = tid >> 6, lane = tid & 63;
  const int wm = w >> 1, wn = w & 1;
  const int lr = lane & 15, lg = lane >> 4;
  const int cw = (lg ^ ((lr >> 1) & 3)) * 8;
  const u16* Ab = A + (size_t)bm * 128 * K;
  const u16* Bb = Bm + (size_t)bn * 128 * K;
  const int NT = K >> 6;

  auto stage = [&](const u16* gb, u16* region, int tile, int kh) {
#pragma unroll
    for (int i = 0; i < 2; i++) {
      int q = tid + i * 256;
      int row = q >> 2, ch = q & 3;
      int sc = ch ^ ((row >> 1) & 3);
      stage16(gb + (size_t)row * K + tile * 64 + kh * 32 + sc * 8, region + q * 8);
    }
  };

  fx4 acc[4][4];
  const fx4 zero4 = {0.f, 0.f, 0.f, 0.f};
#pragma unroll
  for (int m = 0; m < 4; m++)
#pragma unroll
    for (int n = 0; n < 4; n++) acc[m][n] = zero4;

  stage(Ab, &As[0][0][0], 0, 0);
  stage(Bb, &Bs[0][0][0], 0, 0);
  stage(Ab, &As[0][1][0], 0, 1);
  stage(Bb, &Bs[0][1][0], 0, 1);
  stage(Ab, &As[1][0][0], 1, 0);
  stage(Bb, &Bs[1][0][0], 1, 0);
  asm volatile("s_waitcnt vmcnt(4)" ::: "memory");
  __builtin_amdgcn_s_barrier();

  const int arow = (wm * 64 + lr) * 32;
  const int brow = (wn * 64 + lr) * 32;
  bfx8 af[4], bf[4];

#pragma unroll 1
  for (int t = 0; t < NT; t++) {
    const u16* A0 = &As[t & 1][0][0];
    const u16* A1 = &As[t & 1][1][0];
    const u16* B0 = &Bs[t & 1][0][0];
    const u16* B1 = &Bs[t & 1][1][0];
    const int p1 = (t + 1) & 1, p2 = t & 1;

    // phase A: kh0
#pragma unroll
    for (int mi = 0; mi < 4; mi++) af[mi] = *(const bfx8*)(A0 + arow + mi * 512 + cw);
#pragma unroll
    for (int n = 0; n < 4; n++) bf[n] = *(const bfx8*)(B0 + brow + n * 512 + cw);
    if (t + 1 < NT) {
      stage(Ab, &As[p1][1][0], t + 1, 1);
      stage(Bb, &Bs[p1][1][0], t + 1, 1);
    }
    __builtin_amdgcn_s_barrier();
    __builtin_amdgcn_s_setprio(1);
#pragma unroll
    for (int mi = 0; mi < 4; mi++)
#pragma unroll
      for (int n = 0; n < 4; n++)
        acc[mi][n] = __builtin_amdgcn_mfma_f32_16x16x32_bf16(af[mi], bf[n], acc[mi][n], 0, 0, 0);
    __builtin_amdgcn_s_setprio(0);
    __builtin_amdgcn_s_barrier();

    // phase B: kh1
#pragma unroll
    for (int mi = 0; mi < 4; mi++) af[mi] = *(const bfx8*)(A1 + arow + mi * 512 + cw);
#pragma unroll
    for (int n = 0; n < 4; n++) bf[n] = *(const bfx8*)(B1 + brow + n * 512 + cw);
    if (t + 2 < NT) {
      stage(Ab, &As[p2][0][0], t + 2, 0);
      stage(Bb, &Bs[p2][0][0], t + 2, 0);
    }
    __builtin_amdgcn_s_barrier();
    __builtin_amdgcn_s_setprio(1);
#pragma unroll
    for (int mi = 0; mi < 4; mi++)
#pragma unroll
      for (int n = 0; n < 4; n++)
        acc[mi][n] = __builtin_amdgcn_mfma_f32_16x16x32_bf16(af[mi], bf[n], acc[mi][n], 0, 0, 0);
    __builtin_amdgcn_s_setprio(0);
    if (t + 2 < NT) {
      asm volatile("s_waitcnt vmcnt(4)" ::: "memory");
    } else {
      asm volatile("s_waitcnt vmcnt(0)" ::: "memory");  // tail drain (race fix)
    }
    __builtin_amdgcn_s_barrier();
  }

  const int r0 = bm * 128 + wm * 64, c0 = bn * 128 + wn * 64;
#pragma unroll
  for (int m = 0; m < 4; m++) {
#pragma unroll
    for (int n = 0; n < 4; n++) {
      int c = c0 + n * 16 + lr;
#pragma unroll
      for (int i = 0; i < 4; i++)
        C[(size_t)(r0 + m * 16 + lg * 4 + i) * N + c] = acc[m][n][i] + bias[c];
    }
  }
}

// ---------------- Q/K epilogue: rmsnorm + rope, relayout ----------------
__global__ __launch_bounds__(256) void k_qkpost(const u16* __restrict__ qkv,
                                                const float* __restrict__ cosp,
                                                const float* __restrict__ sinp,
                                                const float* __restrict__ gq,
                                                const float* __restrict__ gk,
                                                u16* __restrict__ Qo,
                                                u16* __restrict__ Ko) {
  int bi = blockIdx.x;
  int hh = bi % 24;
  int t64 = (bi / 24) % 32;
  int b = bi / 768;
  int tid = threadIdx.x;
  int j = tid >> 2, p = tid & 3;
  int t = t64 * 64 + j;
  bool isq = hh < 16;
  int colbase = isq ? hh * 128 : 2048 + (hh - 16) * 128;
  const u16* src = qkv + ((size_t)(b * T_ + t)) * NQKV + colbase + p * 32;

  float xv[32];
#pragma unroll
  for (int c = 0; c < 4; c++) {
    uint4 raw = *(const uint4*)(src + c * 8);
    u32 wd[4] = {raw.x, raw.y, raw.z, raw.w};
#pragma unroll
    for (int q2 = 0; q2 < 4; q2++) {
      xv[c * 8 + q2 * 2 + 0] = __uint_as_float(wd[q2] << 16);
      xv[c * 8 + q2 * 2 + 1] = __uint_as_float(wd[q2] & 0xffff0000u);
    }
  }
  float ss = 0.f;
#pragma unroll
  for (int i = 0; i < 32; i++) ss += xv[i] * xv[i];
  ss += __shfl_xor(ss, 1);
  ss += __shfl_xor(ss, 2);
  float rinv = rsqrtf(ss * (1.0f / 128.0f) + 1e-6f);
  const float* g = isq ? gq : gk;
  const float* cr = cosp + (size_t)t * 128 + p * 32;
  const float* sr = sinp + (size_t)t * 128 + p * 32;

  float ov[32];
#pragma unroll
  for (int i = 0; i < 32; i++) {
    float y = xv[i] * rinv * g[p * 32 + i];
    float oth = __shfl_xor(y, 2);
    float rot = (p < 2) ? -oth : oth;
    ov[i] = y * cr[i] + rot * sr[i];
  }

  uint4 pk[4];
#pragma unroll
  for (int c = 0; c < 4; c++) {
    u32 wd[4];
#pragma unroll
    for (int q2 = 0; q2 < 4; q2++)
      wd[q2] = (u32)f2bf(ov[c * 8 + q2 * 2]) | ((u32)f2bf(ov[c * 8 + q2 * 2 + 1]) << 16);
    pk[c] = make_uint4(wd[0], wd[1], wd[2], wd[3]);
  }

  if (isq) {
    u16* dst = Qo + (((size_t)(b * NH + hh)) * T_ + t) * HD + p * 32;
#pragma unroll
    for (int c = 0; c < 4; c++) *(uint4*)(dst + c * 8) = pk[c];
  } else {
    int hk = hh - 16;
    u16* dstrow = Ko + (((size_t)(b * NKV + hk)) * T_ + t) * HD;
#pragma unroll
    for (int c = 0; c < 4; c++) {
      int C = p * 4 + c;
      int Cs = C ^ (t & 7);  // XOR swizzle (16 chunks/row), matches attn read
      *(uint4*)(dstrow + Cs * 8) = pk[c];
    }
  }
}

// ---------------- V transpose: qkv[...,3072+] -> vt[b][hkv][d][t] ----------------
__global__ __launch_bounds__(256) void k_vtr(const u16* __restrict__ qkv,
                                             u16* __restrict__ vt) {
  __shared__ __align__(16) u16 sm[128 * 64];
  int bi = blockIdx.x;
  int hv = bi & 7;
  int t64 = (bi >> 3) & 31;
  int b = bi >> 8;
  int tid = threadIdx.x;
#pragma unroll
  for (int it = 0; it < 4; it++) {
    int idx = tid + it * 256;
    int tok = idx >> 4, c = idx & 15;
    uint4 raw = *(const uint4*)(qkv + ((size_t)(b * T_ + t64 * 64 + tok)) * NQKV +
                                3072 + hv * 128 + c * 8);
    u32 wd[4] = {raw.x, raw.y, raw.z, raw.w};
#pragma unroll
    for (int q2 = 0; q2 < 4; q2++) {
      sm[(c * 8 + q2 * 2 + 0) * 64 + tok] = (u16)(wd[q2] & 0xffffu);
      sm[(c * 8 + q2 * 2 + 1) * 64 + tok] = (u16)(wd[q2] >> 16);
    }
  }
  __syncthreads();
  int d = tid >> 1, half = tid & 1;
  size_t rowb = (((size_t)(b * NKV + hv)) * HD + d) * T_ + t64 * 64;
#pragma unroll
  for (int c = 0; c < 4; c++) {
    int cg = half * 4 + c;
    int cs = cg ^ (d & 7);
    u32 wd[4];
#pragma unroll
    for (int q2 = 0; q2 < 4; q2++) {
      u32 lo = sm[d * 64 + half * 32 + c * 8 + 2 * q2];
      u32 hi = sm[d * 64 + half * 32 + c * 8 + 2 * q2 + 1];
      wd[q2] = lo | (hi << 16);
    }
    *(uint4*)(vt + rowb + cs * 8) = make_uint4(wd[0], wd[1], wd[2], wd[3]);
  }
}

// ---------------- flash attention v5 (r11 verbatim, PASSING ~72us) ----------
__global__ __launch_bounds__(512, 4) void k_attn(const u16* __restrict__ Qg,
                                                 const u16* __restrict__ Kg,
                                                 const u16* __restrict__ Vg,
                                                 u16* __restrict__ Og) {
  __shared__ __align__(16) u16 Ks[2][64 * 128];
  __shared__ __align__(16) u16 Vs[2][128 * 64];
  __shared__ __align__(16) u16 Ps[8][16 * 64];
  const int bi = blockIdx.x;
  const int zr = bi & 15, h = (bi >> 4) & 15, b = bi >> 8;
  const int z = b ? (15 - zr) : zr;
  const int hkv = h >> 1;
  const int tid = threadIdx.x, w = tid >> 6, lane = tid & 63;
  const int lr = lane & 15, lg = lane >> 4;
  const int zt = (w < 4) ? z : (31 - z);
  const int qr0 = zt * 64 + (w & 3) * 16;
  const int qrow = qr0 + lr;
  const int nch = 32 - z;
  const int myl = zt + 1;

  const u16* kb = Kg + ((size_t)(b * NKV + hkv)) * T_ * HD;
  const u16* vb = Vg + ((size_t)(b * NKV + hkv)) * HD * T_;
  u16* pw = &Ps[w][0];
  const fx4 zero4 = {0.f, 0.f, 0.f, 0.f};

  auto stageKV = [&](int buf, int kv0) {
    u16* Kd = &Ks[buf][0];
    u16* Vd = &Vs[buf][0];
#pragma unroll
    for (int it = 0; it < 2; it++) {
      int r = it * 32 + (tid >> 4);
      stage16(kb + (size_t)(kv0 + r) * HD + (tid & 15) * 8, Kd + it * 4096 + tid * 8);
      int d = it * 64 + (tid >> 3);
      stage16(vb + (size_t)d * T_ + kv0 + (tid & 7) * 8, Vd + it * 4096 + tid * 8);
    }
  };

  const u16* qbase = Qg + (((size_t)(b * NH + h)) * T_ + qrow) * HD;
  bfx8 qf[4];
#pragma unroll
  for (int kk = 0; kk < 4; kk++) qf[kk] = *(const bfx8*)(qbase + kk * 32 + lg * 8);

  fx4 o[8];
#pragma unroll
  for (int nf = 0; nf < 8; nf++) o[nf] = zero4;
  float l_i = 0.f;

  stageKV(0, 0);
  asm volatile("s_waitcnt vmcnt(0)" ::: "memory");
  __builtin_amdgcn_s_barrier();
  int cur = 0;

#pragma unroll 1
  for (int ch = 0; ch < nch; ch++) {
    if (ch + 1 < nch) {
      stageKV(cur ^ 1, (ch + 1) * 64);
      asm volatile("s_waitcnt vmcnt(4)" ::: "memory");
    } else {
      asm volatile("s_waitcnt vmcnt(0)" ::: "memory");
    }
    __builtin_amdgcn_s_barrier();

    if (ch < myl) {
      const u16* Kd = &Ks[cur][0];
      const u16* Vd = &Vs[cur][0];
      const int kv0 = ch * 64;
      const bool diag = (ch == zt);

      fx4 sa[4];
#pragma unroll
      for (int n = 0; n < 4; n++) sa[n] = zero4;
      __builtin_amdgcn_s_setprio(1);
#pragma unroll
      for (int n = 0; n < 4; n++) {
        const int kvl = n * 16 + lr;
        const u16* krow = Kd + kvl * 128;
#pragma unroll
        for (int kk = 0; kk < 4; kk++) {
          int cs = (kk * 4 + lg) ^ (kvl & 7);
          bfx8 kf = *(const bfx8*)(krow + cs * 8);
          sa[n] = __builtin_amdgcn_mfma_f32_16x16x32_bf16(kf, qf[kk], sa[n], 0, 0, 0);
        }
      }
      __builtin_amdgcn_s_setprio(0);

#pragma unroll
      for (int n = 0; n < 4; n++) {
        float p0 = exp2f(sa[n][0] * SC2_);
        float p1 = exp2f(sa[n][1] * SC2_);
        float p2 = exp2f(sa[n][2] * SC2_);
        float p3 = exp2f(sa[n][3] * SC2_);
        if (diag) {
          int kvg = kv0 + n * 16 + 4 * lg;
          p0 = (kvg + 0 > qrow) ? 0.f : p0;
          p1 = (kvg + 1 > qrow) ? 0.f : p1;
          p2 = (kvg + 2 > qrow) ? 0.f : p2;
          p3 = (kvg + 3 > qrow) ? 0.f : p3;
        }
        l_i += (p0 + p1) + (p2 + p3);
        u32 w0 = cvtpk(p0, p1);
        u32 w1 = cvtpk(p2, p3);
        int c = 2 * n + (lg >> 1);
        int cs = c ^ (lr & 7);
        *(uint2*)(pw + lr * 64 + cs * 8 + 4 * (lg & 1)) = make_uint2(w0, w1);
      }
      asm volatile("s_waitcnt lgkmcnt(0)" ::: "memory");
      __builtin_amdgcn_sched_barrier(0);

      bfx8 pa[2];
#pragma unroll
      for (int ks = 0; ks < 2; ks++) {
        int cp = (4 * ks + lg) ^ (lr & 7);
        pa[ks] = *(const bfx8*)(pw + lr * 64 + cp * 8);
      }
      __builtin_amdgcn_s_setprio(1);
#pragma unroll
      for (int nf = 0; nf < 8; nf++) {
        int d = nf * 16 + lr;
        const u16* vrow = Vd + d * 64;
#pragma unroll
        for (int ks = 0; ks < 2; ks++) {
          int cv = (4 * ks + lg) ^ (d & 7);
          bfx8 vf = *(const bfx8*)(vrow + cv * 8);
          o[nf] = __builtin_amdgcn_mfma_f32_16x16x32_bf16(pa[ks], vf, o[nf], 0, 0, 0);
        }
      }
      __builtin_amdgcn_s_setprio(0);
    }
    __builtin_amdgcn_s_barrier();
    cur ^= 1;
  }

  float lt = l_i + __shfl_xor(l_i, 16);
  lt += __shfl_xor(lt, 32);
  float inv[4];
#pragma unroll
  for (int i = 0; i < 4; i++) inv[i] = 1.0f / __shfl(lt, 4 * lg + i);
  u16* ob = Og + ((size_t)(b * T_ + qr0)) * DM + h * HD;
#pragma unroll
  for (int nf = 0; nf < 8; nf++)
#pragma unroll
    for (int i = 0; i < 4; i++)
      ob[(size_t)(4 * lg + i) * DM + nf * 16 + lr] = f2bf(o[nf][i] * inv[i]);
}

// ---------------- launch ----------------
extern "C" void kernel_launch(void* const* d_in, const int* in_sizes, int n_in,
                              void* d_out, int out_size, void* d_ws, size_t ws_size,
                              hipStream_t stream) {
  const float* x = (const float*)d_in[0];
  const float* cosp = (const float*)d_in[2];
  const float* sinp = (const float*)d_in[3];
  const float* Wq = (const float*)d_in[4];
  const float* Wk = (const float*)d_in[5];
  const float* Wv = (const float*)d_in[6];
  const float* Wo = (const float*)d_in[7];
  const float* bo = (const float*)d_in[8];
  const float* gq = (const float*)d_in[9];
  const float* gk = (const float*)d_in[10];

  char* ws = (char*)d_ws;
  u16* xbf  = (u16*)(ws + 0);           // 16 MB
  u16* wqkv = (u16*)(ws + 16777216);    // 16 MB (contiguous with wo below)
  u16* wo   = (u16*)(ws + 33554432);    // 8 MB
  u16* qkv  = (u16*)(ws + 41943040);    // 32 MB
  u16* qb   = (u16*)(ws + 75497472);    // 16 MB
  u16* kb   = (u16*)(ws + 92274688);    // 8 MB
  u16* vt   = (u16*)(ws + 100663296);   // 8 MB
  u16* ab   = (u16*)(ws + 109051904);   // 16 MB
  float* out = (float*)d_out;

  k_cvt<<<8192, 256, 0, stream>>>(x, xbf, 8388608);
  k_cvtw<<<12288, 256, 0, stream>>>(Wq, Wk, Wv, Wo, wqkv);

  k_gemm256<<<512, 256, 0, stream>>>(xbf, wqkv, qkv, 4096, 4096, 2048);
  k_qkpost<<<1536, 256, 0, stream>>>(qkv, cosp, sinp, gq, gk, qb, kb);
  k_vtr<<<512, 256, 0, stream>>>(qkv, vt);
  k_attn<<<512, 512, 0, stream>>>(qb, kb, vt, ab);
  k_gemmo<<<512, 256, 0, stream>>>(ab, wo, out, bo, 4096, 2048, 2048);
}

// Round 17
// 232.507 us; speedup vs baseline: 1.0130x; 1.0130x over previous
//
#include <hip/hip_runtime.h>
#include <stdint.h>

#define B_ 2
#define T_ 2048
#define DM 2048
#define NH 16
#define NKV 8
#define HD 128
#define NQKV 4096
#define SC2_ 0.12753102765f  // (1/sqrt(128)) * log2(e)

typedef float fx4 __attribute__((ext_vector_type(4)));
typedef __bf16 bfx8 __attribute__((ext_vector_type(8)));
typedef unsigned short u16;
typedef unsigned int u32;

typedef __attribute__((address_space(1))) const void gas_t;
typedef __attribute__((address_space(3))) void las_t;

__device__ __forceinline__ u16 f2bf(float f) {
  u32 u = __float_as_uint(f);
  u = (u + 0x7fffu + ((u >> 16) & 1u)) >> 16;
  return (u16)u;
}

// HW packed f32->bf16 pair (T12): lo -> bits[15:0], hi -> bits[31:16]
__device__ __forceinline__ u32 cvtpk(float lo, float hi) {
  u32 r;
  asm("v_cvt_pk_bf16_f32 %0, %1, %2" : "=v"(r) : "v"(lo), "v"(hi));
  return r;
}

// async global->LDS, 16B per lane; lds arg must be wave-uniform base + lane*16
__device__ __forceinline__ void stage16(const void* g, void* l) {
  __builtin_amdgcn_global_load_lds((gas_t*)(uintptr_t)g, (las_t*)(uintptr_t)l,
                                   16, 0, 0);
}

// ---------------- fused fp32->bf16 convert: x | Wq | Wk | Wv | Wo ----------------
// grid 20480 x 256 x 4 elems = 20,971,520 = 8,388,608 (x) + 12,582,912 (weights)
__global__ void k_cvtall(const float* __restrict__ x, const float* __restrict__ wq,
                         const float* __restrict__ wk, const float* __restrict__ wv,
                         const float* __restrict__ wo, u16* __restrict__ xbf,
                         u16* __restrict__ wout) {
  int i = (blockIdx.x * blockDim.x + threadIdx.x) * 4;
  const float* src;
  u16* dst;
  int off;
  if (i < 8388608) { src = x; dst = xbf; off = i; }
  else {
    int j = i - 8388608;
    dst = wout;
    if (j < 4194304) { src = wq; off = j; }
    else if (j < 6291456) { src = wk; off = j - 4194304; }
    else if (j < 8388608) { src = wv; off = j - 6291456; }
    else { src = wo; off = j - 8388608; }
    dst = wout + (i - 8388608);
    off = off;  // src offset computed above
    float4 v = *(const float4*)(src + off);
    u32 w0 = (u32)f2bf(v.x) | ((u32)f2bf(v.y) << 16);
    u32 w1 = (u32)f2bf(v.z) | ((u32)f2bf(v.w) << 16);
    *(uint2*)dst = make_uint2(w0, w1);
    return;
  }
  float4 v = *(const float4*)(src + off);
  u32 w0 = (u32)f2bf(v.x) | ((u32)f2bf(v.y) << 16);
  u32 w1 = (u32)f2bf(v.z) | ((u32)f2bf(v.w) << 16);
  *(uint2*)(dst + off) = make_uint2(w0, w1);
}

// ======== QKV GEMM: 128x256 tile, BK=32 dbuf, grid 512, XCD-chunked swizzle ========
__global__ __launch_bounds__(256, 2) void k_gemm256(const u16* __restrict__ A,
                                                    const u16* __restrict__ Bm,
                                                    u16* __restrict__ C,
                                                    int M, int N, int K) {
  __shared__ __align__(16) u16 As[2][128 * 32];
  __shared__ __align__(16) u16 Bs[2][256 * 32];
  const int nbn = N >> 8;
  // T1: XCD-aware swizzle (512 blocks, bijective): XCD x owns sw in [x*64, x*64+64)
  const int bid = blockIdx.x;
  const int sw = ((bid & 7) << 6) | (bid >> 3);
  const int bm = sw / nbn, bn = sw % nbn;
  const int tid = threadIdx.x;
  const int w = tid >> 6, lane = tid & 63;
  const int lr = lane & 15, lg = lane >> 4;
  const int cw = (lg ^ ((lr >> 1) & 3)) * 8;
  const u16* Ab = A + (size_t)bm * 128 * K;
  const u16* Bb = Bm + (size_t)bn * 256 * K;
  const int NT = K >> 5;

  auto stage = [&](int buf, int tile) {
    u16* Ad = &As[buf][0];
    u16* Bd = &Bs[buf][0];
#pragma unroll
    for (int i = 0; i < 2; i++) {
      int q = tid + i * 256;
      int row = q >> 2, ch = q & 3;
      int sc = ch ^ ((row >> 1) & 3);
      stage16(Ab + (size_t)row * K + tile * 32 + sc * 8, Ad + q * 8);
    }
#pragma unroll
    for (int i = 0; i < 4; i++) {
      int q = tid + i * 256;
      int row = q >> 2, ch = q & 3;
      int sc = ch ^ ((row >> 1) & 3);
      stage16(Bb + (size_t)row * K + tile * 32 + sc * 8, Bd + q * 8);
    }
  };

  fx4 acc[8][4];
  const fx4 zero4 = {0.f, 0.f, 0.f, 0.f};
#pragma unroll
  for (int m = 0; m < 8; m++)
#pragma unroll
    for (int n = 0; n < 4; n++) acc[m][n] = zero4;

  stage(0, 0);
  asm volatile("s_waitcnt vmcnt(0)" ::: "memory");
  __builtin_amdgcn_s_barrier();

  const int arow = lr * 32;
  const int brow = (w * 64 + lr) * 32;
  bfx8 af[8], bf[4];

#pragma unroll 1
  for (int t = 0; t < NT; t++) {
    const int cur = t & 1;
    if (t + 1 < NT) {
      stage(cur ^ 1, t + 1);
      asm volatile("s_waitcnt vmcnt(6)" ::: "memory");
    } else {
      asm volatile("s_waitcnt vmcnt(0)" ::: "memory");  // tail drain (race fix)
    }
    __builtin_amdgcn_s_barrier();

    const u16* A0 = &As[cur][0];
    const u16* B0 = &Bs[cur][0];
#pragma unroll
    for (int mi = 0; mi < 8; mi++) af[mi] = *(const bfx8*)(A0 + arow + mi * 512 + cw);
#pragma unroll
    for (int n = 0; n < 4; n++) bf[n] = *(const bfx8*)(B0 + brow + n * 512 + cw);
    __builtin_amdgcn_s_setprio(1);
#pragma unroll
    for (int mi = 0; mi < 8; mi++)
#pragma unroll
      for (int n = 0; n < 4; n++)
        acc[mi][n] = __builtin_amdgcn_mfma_f32_16x16x32_bf16(af[mi], bf[n], acc[mi][n], 0, 0, 0);
    __builtin_amdgcn_s_setprio(0);
    __builtin_amdgcn_s_barrier();
  }

  const int r0 = bm * 128, c0 = bn * 256 + w * 64;
#pragma unroll
  for (int m = 0; m < 8; m++) {
#pragma unroll
    for (int n = 0; n < 4; n++) {
      int c = c0 + n * 16 + lr;
#pragma unroll
      for (int i = 0; i < 4; i++)
        C[(size_t)(r0 + m * 16 + lg * 4 + i) * N + c] = f2bf(acc[m][n][i]);
    }
  }
}

// ======== 128x128 GEMM, 2 merged phases/K-tile, f32+bias out, XCD swizzle ========
__global__ __launch_bounds__(256, 2) void k_gemmo(const u16* __restrict__ A,
                                                  const u16* __restrict__ Bm,
                                                  float* __restrict__ C,
                                                  const float* __restrict__ bias,
                                                  int M, int N, int K) {
  __shared__ __align__(16) u16 As[2][2][128 * 32];
  __shared__ __align__(16) u16 Bs[2][2][128 * 32];
  const int nbn = N >> 7;
  const int bid = blockIdx.x;
  const int sw = ((bid & 7) << 6) | (bid >> 3);  // 512 blocks, bijective
  const int bm = sw / nbn, bn = sw % nbn;
  const int tid = threadIdx.x;
  const int w = tid >> 6, lane = tid & 63;
  const int wm = w >> 1, wn = w & 1;
  const int lr = lane & 15, lg = lane >> 4;
  const int cw = (lg ^ ((lr >> 1) & 3)) * 8;
  const u16* Ab = A + (size_t)bm * 128 * K;
  const u16* Bb = Bm + (size_t)bn * 128 * K;
  const int NT = K >> 6;

  auto stage = [&](const u16* gb, u16* region, int tile, int kh) {
#pragma unroll
    for (int i = 0; i < 2; i++) {
      int q = tid + i * 256;
      int row = q >> 2, ch = q & 3;
      int sc = ch ^ ((row >> 1) & 3);
      stage16(gb + (size_t)row * K + tile * 64 + kh * 32 + sc * 8, region + q * 8);
    }
  };

  fx4 acc[4][4];
  const fx4 zero4 = {0.f, 0.f, 0.f, 0.f};
#pragma unroll
  for (int m = 0; m < 4; m++)
#pragma unroll
    for (int n = 0; n < 4; n++) acc[m][n] = zero4;

  stage(Ab, &As[0][0][0], 0, 0);
  stage(Bb, &Bs[0][0][0], 0, 0);
  stage(Ab, &As[0][1][0], 0, 1);
  stage(Bb, &Bs[0][1][0], 0, 1);
  stage(Ab, &As[1][0][0], 1, 0);
  stage(Bb, &Bs[1][0][0], 1, 0);
  asm volatile("s_waitcnt vmcnt(4)" ::: "memory");
  __builtin_amdgcn_s_barrier();

  const int arow = (wm * 64 + lr) * 32;
  const int brow = (wn * 64 + lr) * 32;
  bfx8 af[4], bf[4];

#pragma unroll 1
  for (int t = 0; t < NT; t++) {
    const u16* A0 = &As[t & 1][0][0];
    const u16* A1 = &As[t & 1][1][0];
    const u16* B0 = &Bs[t & 1][0][0];
    const u16* B1 = &Bs[t & 1][1][0];
    const int p1 = (t + 1) & 1, p2 = t & 1;

    // phase A: kh0
#pragma unroll
    for (int mi = 0; mi < 4; mi++) af[mi] = *(const bfx8*)(A0 + arow + mi * 512 + cw);
#pragma unroll
    for (int n = 0; n < 4; n++) bf[n] = *(const bfx8*)(B0 + brow + n * 512 + cw);
    if (t + 1 < NT) {
      stage(Ab, &As[p1][1][0], t + 1, 1);
      stage(Bb, &Bs[p1][1][0], t + 1, 1);
    }
    __builtin_amdgcn_s_barrier();
    __builtin_amdgcn_s_setprio(1);
#pragma unroll
    for (int mi = 0; mi < 4; mi++)
#pragma unroll
      for (int n = 0; n < 4; n++)
        acc[mi][n] = __builtin_amdgcn_mfma_f32_16x16x32_bf16(af[mi], bf[n], acc[mi][n], 0, 0, 0);
    __builtin_amdgcn_s_setprio(0);
    __builtin_amdgcn_s_barrier();

    // phase B: kh1
#pragma unroll
    for (int mi = 0; mi < 4; mi++) af[mi] = *(const bfx8*)(A1 + arow + mi * 512 + cw);
#pragma unroll
    for (int n = 0; n < 4; n++) bf[n] = *(const bfx8*)(B1 + brow + n * 512 + cw);
    if (t + 2 < NT) {
      stage(Ab, &As[p2][0][0], t + 2, 0);
      stage(Bb, &Bs[p2][0][0], t + 2, 0);
    }
    __builtin_amdgcn_s_barrier();
    __builtin_amdgcn_s_setprio(1);
#pragma unroll
    for (int mi = 0; mi < 4; mi++)
#pragma unroll
      for (int n = 0; n < 4; n++)
        acc[mi][n] = __builtin_amdgcn_mfma_f32_16x16x32_bf16(af[mi], bf[n], acc[mi][n], 0, 0, 0);
    __builtin_amdgcn_s_setprio(0);
    if (t + 2 < NT) {
      asm volatile("s_waitcnt vmcnt(4)" ::: "memory");
    } else {
      asm volatile("s_waitcnt vmcnt(0)" ::: "memory");  // tail drain (race fix)
    }
    __builtin_amdgcn_s_barrier();
  }

  const int r0 = bm * 128 + wm * 64, c0 = bn * 128 + wn * 64;
#pragma unroll
  for (int m = 0; m < 4; m++) {
#pragma unroll
    for (int n = 0; n < 4; n++) {
      int c = c0 + n * 16 + lr;
#pragma unroll
      for (int i = 0; i < 4; i++)
        C[(size_t)(r0 + m * 16 + lg * 4 + i) * N + c] = acc[m][n][i] + bias[c];
    }
  }
}

// ---------------- Q/K epilogue: rmsnorm + rope, relayout ----------------
__global__ __launch_bounds__(256) void k_qkpost(const u16* __restrict__ qkv,
                                                const float* __restrict__ cosp,
                                                const float* __restrict__ sinp,
                                                const float* __restrict__ gq,
                                                const float* __restrict__ gk,
                                                u16* __restrict__ Qo,
                                                u16* __restrict__ Ko) {
  int bi = blockIdx.x;
  int hh = bi % 24;
  int t64 = (bi / 24) % 32;
  int b = bi / 768;
  int tid = threadIdx.x;
  int j = tid >> 2, p = tid & 3;
  int t = t64 * 64 + j;
  bool isq = hh < 16;
  int colbase = isq ? hh * 128 : 2048 + (hh - 16) * 128;
  const u16* src = qkv + ((size_t)(b * T_ + t)) * NQKV + colbase + p * 32;

  float xv[32];
#pragma unroll
  for (int c = 0; c < 4; c++) {
    uint4 raw = *(const uint4*)(src + c * 8);
    u32 wd[4] = {raw.x, raw.y, raw.z, raw.w};
#pragma unroll
    for (int q2 = 0; q2 < 4; q2++) {
      xv[c * 8 + q2 * 2 + 0] = __uint_as_float(wd[q2] << 16);
      xv[c * 8 + q2 * 2 + 1] = __uint_as_float(wd[q2] & 0xffff0000u);
    }
  }
  float ss = 0.f;
#pragma unroll
  for (int i = 0; i < 32; i++) ss += xv[i] * xv[i];
  ss += __shfl_xor(ss, 1);
  ss += __shfl_xor(ss, 2);
  float rinv = rsqrtf(ss * (1.0f / 128.0f) + 1e-6f);
  const float* g = isq ? gq : gk;
  const float* cr = cosp + (size_t)t * 128 + p * 32;
  const float* sr = sinp + (size_t)t * 128 + p * 32;

  float ov[32];
#pragma unroll
  for (int i = 0; i < 32; i++) {
    float y = xv[i] * rinv * g[p * 32 + i];
    float oth = __shfl_xor(y, 2);
    float rot = (p < 2) ? -oth : oth;
    ov[i] = y * cr[i] + rot * sr[i];
  }

  uint4 pk[4];
#pragma unroll
  for (int c = 0; c < 4; c++) {
    u32 wd[4];
#pragma unroll
    for (int q2 = 0; q2 < 4; q2++)
      wd[q2] = (u32)f2bf(ov[c * 8 + q2 * 2]) | ((u32)f2bf(ov[c * 8 + q2 * 2 + 1]) << 16);
    pk[c] = make_uint4(wd[0], wd[1], wd[2], wd[3]);
  }

  if (isq) {
    u16* dst = Qo + (((size_t)(b * NH + hh)) * T_ + t) * HD + p * 32;
#pragma unroll
    for (int c = 0; c < 4; c++) *(uint4*)(dst + c * 8) = pk[c];
  } else {
    int hk = hh - 16;
    u16* dstrow = Ko + (((size_t)(b * NKV + hk)) * T_ + t) * HD;
#pragma unroll
    for (int c = 0; c < 4; c++) {
      int C = p * 4 + c;
      int Cs = C ^ (t & 7);  // XOR swizzle (16 chunks/row), matches attn read
      *(uint4*)(dstrow + Cs * 8) = pk[c];
    }
  }
}

// ---------------- V transpose: qkv[...,3072+] -> vt[b][hkv][d][t] ----------------
__global__ __launch_bounds__(256) void k_vtr(const u16* __restrict__ qkv,
                                             u16* __restrict__ vt) {
  __shared__ __align__(16) u16 sm[128 * 64];
  int bi = blockIdx.x;
  int hv = bi & 7;
  int t64 = (bi >> 3) & 31;
  int b = bi >> 8;
  int tid = threadIdx.x;
#pragma unroll
  for (int it = 0; it < 4; it++) {
    int idx = tid + it * 256;
    int tok = idx >> 4, c = idx & 15;
    uint4 raw = *(const uint4*)(qkv + ((size_t)(b * T_ + t64 * 64 + tok)) * NQKV +
                                3072 + hv * 128 + c * 8);
    u32 wd[4] = {raw.x, raw.y, raw.z, raw.w};
#pragma unroll
    for (int q2 = 0; q2 < 4; q2++) {
      sm[(c * 8 + q2 * 2 + 0) * 64 + tok] = (u16)(wd[q2] & 0xffffu);
      sm[(c * 8 + q2 * 2 + 1) * 64 + tok] = (u16)(wd[q2] >> 16);
    }
  }
  __syncthreads();
  int d = tid >> 1, half = tid & 1;
  size_t rowb = (((size_t)(b * NKV + hv)) * HD + d) * T_ + t64 * 64;
#pragma unroll
  for (int c = 0; c < 4; c++) {
    int cg = half * 4 + c;
    int cs = cg ^ (d & 7);
    u32 wd[4];
#pragma unroll
    for (int q2 = 0; q2 < 4; q2++) {
      u32 lo = sm[d * 64 + half * 32 + c * 8 + 2 * q2];
      u32 hi = sm[d * 64 + half * 32 + c * 8 + 2 * q2 + 1];
      wd[q2] = lo | (hi << 16);
    }
    *(uint4*)(vt + rowb + cs * 8) = make_uint4(wd[0], wd[1], wd[2], wd[3]);
  }
}

// ---------------- flash attention v5 (r11 verbatim, PASSING ~72us) ----------
__global__ __launch_bounds__(512, 4) void k_attn(const u16* __restrict__ Qg,
                                                 const u16* __restrict__ Kg,
                                                 const u16* __restrict__ Vg,
                                                 u16* __restrict__ Og) {
  __shared__ __align__(16) u16 Ks[2][64 * 128];
  __shared__ __align__(16) u16 Vs[2][128 * 64];
  __shared__ __align__(16) u16 Ps[8][16 * 64];
  const int bi = blockIdx.x;
  const int zr = bi & 15, h = (bi >> 4) & 15, b = bi >> 8;
  const int z = b ? (15 - zr) : zr;
  const int hkv = h >> 1;
  const int tid = threadIdx.x, w = tid >> 6, lane = tid & 63;
  const int lr = lane & 15, lg = lane >> 4;
  const int zt = (w < 4) ? z : (31 - z);
  const int qr0 = zt * 64 + (w & 3) * 16;
  const int qrow = qr0 + lr;
  const int nch = 32 - z;
  const int myl = zt + 1;

  const u16* kb = Kg + ((size_t)(b * NKV + hkv)) * T_ * HD;
  const u16* vb = Vg + ((size_t)(b * NKV + hkv)) * HD * T_;
  u16* pw = &Ps[w][0];
  const fx4 zero4 = {0.f, 0.f, 0.f, 0.f};

  auto stageKV = [&](int buf, int kv0) {
    u16* Kd = &Ks[buf][0];
    u16* Vd = &Vs[buf][0];
#pragma unroll
    for (int it = 0; it < 2; it++) {
      int r = it * 32 + (tid >> 4);
      stage16(kb + (size_t)(kv0 + r) * HD + (tid & 15) * 8, Kd + it * 4096 + tid * 8);
      int d = it * 64 + (tid >> 3);
      stage16(vb + (size_t)d * T_ + kv0 + (tid & 7) * 8, Vd + it * 4096 + tid * 8);
    }
  };

  const u16* qbase = Qg + (((size_t)(b * NH + h)) * T_ + qrow) * HD;
  bfx8 qf[4];
#pragma unroll
  for (int kk = 0; kk < 4; kk++) qf[kk] = *(const bfx8*)(qbase + kk * 32 + lg * 8);

  fx4 o[8];
#pragma unroll
  for (int nf = 0; nf < 8; nf++) o[nf] = zero4;
  float l_i = 0.f;

  stageKV(0, 0);
  asm volatile("s_waitcnt vmcnt(0)" ::: "memory");
  __builtin_amdgcn_s_barrier();
  int cur = 0;

#pragma unroll 1
  for (int ch = 0; ch < nch; ch++) {
    if (ch + 1 < nch) {
      stageKV(cur ^ 1, (ch + 1) * 64);
      asm volatile("s_waitcnt vmcnt(4)" ::: "memory");
    } else {
      asm volatile("s_waitcnt vmcnt(0)" ::: "memory");
    }
    __builtin_amdgcn_s_barrier();

    if (ch < myl) {
      const u16* Kd = &Ks[cur][0];
      const u16* Vd = &Vs[cur][0];
      const int kv0 = ch * 64;
      const bool diag = (ch == zt);

      fx4 sa[4];
#pragma unroll
      for (int n = 0; n < 4; n++) sa[n] = zero4;
      __builtin_amdgcn_s_setprio(1);
#pragma unroll
      for (int n = 0; n < 4; n++) {
        const int kvl = n * 16 + lr;
        const u16* krow = Kd + kvl * 128;
#pragma unroll
        for (int kk = 0; kk < 4; kk++) {
          int cs = (kk * 4 + lg) ^ (kvl & 7);
          bfx8 kf = *(const bfx8*)(krow + cs * 8);
          sa[n] = __builtin_amdgcn_mfma_f32_16x16x32_bf16(kf, qf[kk], sa[n], 0, 0, 0);
        }
      }
      __builtin_amdgcn_s_setprio(0);

#pragma unroll
      for (int n = 0; n < 4; n++) {
        float p0 = exp2f(sa[n][0] * SC2_);
        float p1 = exp2f(sa[n][1] * SC2_);
        float p2 = exp2f(sa[n][2] * SC2_);
        float p3 = exp2f(sa[n][3] * SC2_);
        if (diag) {
          int kvg = kv0 + n * 16 + 4 * lg;
          p0 = (kvg + 0 > qrow) ? 0.f : p0;
          p1 = (kvg + 1 > qrow) ? 0.f : p1;
          p2 = (kvg + 2 > qrow) ? 0.f : p2;
          p3 = (kvg + 3 > qrow) ? 0.f : p3;
        }
        l_i += (p0 + p1) + (p2 + p3);
        u32 w0 = cvtpk(p0, p1);
        u32 w1 = cvtpk(p2, p3);
        int c = 2 * n + (lg >> 1);
        int cs = c ^ (lr & 7);
        *(uint2*)(pw + lr * 64 + cs * 8 + 4 * (lg & 1)) = make_uint2(w0, w1);
      }
      asm volatile("s_waitcnt lgkmcnt(0)" ::: "memory");
      __builtin_amdgcn_sched_barrier(0);

      bfx8 pa[2];
#pragma unroll
      for (int ks = 0; ks < 2; ks++) {
        int cp = (4 * ks + lg) ^ (lr & 7);
        pa[ks] = *(const bfx8*)(pw + lr * 64 + cp * 8);
      }
      __builtin_amdgcn_s_setprio(1);
#pragma unroll
      for (int nf = 0; nf < 8; nf++) {
        int d = nf * 16 + lr;
        const u16* vrow = Vd + d * 64;
#pragma unroll
        for (int ks = 0; ks < 2; ks++) {
          int cv = (4 * ks + lg) ^ (d & 7);
          bfx8 vf = *(const bfx8*)(vrow + cv * 8);
          o[nf] = __builtin_amdgcn_mfma_f32_16x16x32_bf16(pa[ks], vf, o[nf], 0, 0, 0);
        }
      }
      __builtin_amdgcn_s_setprio(0);
    }
    __builtin_amdgcn_s_barrier();
    cur ^= 1;
  }

  float lt = l_i + __shfl_xor(l_i, 16);
  lt += __shfl_xor(lt, 32);
  float inv[4];
#pragma unroll
  for (int i = 0; i < 4; i++) inv[i] = 1.0f / __shfl(lt, 4 * lg + i);
  u16* ob = Og + ((size_t)(b * T_ + qr0)) * DM + h * HD;
#pragma unroll
  for (int nf = 0; nf < 8; nf++)
#pragma unroll
    for (int i = 0; i < 4; i++)
      ob[(size_t)(4 * lg + i) * DM + nf * 16 + lr] = f2bf(o[nf][i] * inv[i]);
}

// ---------------- launch ----------------
extern "C" void kernel_launch(void* const* d_in, const int* in_sizes, int n_in,
                              void* d_out, int out_size, void* d_ws, size_t ws_size,
                              hipStream_t stream) {
  const float* x = (const float*)d_in[0];
  const float* cosp = (const float*)d_in[2];
  const float* sinp = (const float*)d_in[3];
  const float* Wq = (const float*)d_in[4];
  const float* Wk = (const float*)d_in[5];
  const float* Wv = (const float*)d_in[6];
  const float* Wo = (const float*)d_in[7];
  const float* bo = (const float*)d_in[8];
  const float* gq = (const float*)d_in[9];
  const float* gk = (const float*)d_in[10];

  char* ws = (char*)d_ws;
  u16* xbf  = (u16*)(ws + 0);           // 16 MB
  u16* wqkv = (u16*)(ws + 16777216);    // 16 MB (contiguous with wo below)
  u16* wo   = (u16*)(ws + 33554432);    // 8 MB
  u16* qkv  = (u16*)(ws + 41943040);    // 32 MB
  u16* qb   = (u16*)(ws + 75497472);    // 16 MB
  u16* kb   = (u16*)(ws + 92274688);    // 8 MB
  u16* vt   = (u16*)(ws + 100663296);   // 8 MB
  u16* ab   = (u16*)(ws + 109051904);   // 16 MB
  float* out = (float*)d_out;

  k_cvtall<<<20480, 256, 0, stream>>>(x, Wq, Wk, Wv, Wo, xbf, wqkv);

  k_gemm256<<<512, 256, 0, stream>>>(xbf, wqkv, qkv, 4096, 4096, 2048);
  k_qkpost<<<1536, 256, 0, stream>>>(qkv, cosp, sinp, gq, gk, qb, kb);
  k_vtr<<<512, 256, 0, stream>>>(qkv, vt);
  k_attn<<<512, 512, 0, stream>>>(qb, kb, vt, ab);
  k_gemmo<<<512, 256, 0, stream>>>(ab, wo, out, bo, 4096, 2048, 2048);
}

// Round 18
// 227.606 us; speedup vs baseline: 1.0348x; 1.0215x over previous
//
#include <hip/hip_runtime.h>
#include <stdint.h>

#define B_ 2
#define T_ 2048
#define DM 2048
#define NH 16
#define NKV 8
#define HD 128
#define NQKV 4096
#define SC2_ 0.12753102765f  // (1/sqrt(128)) * log2(e)

typedef float fx4 __attribute__((ext_vector_type(4)));
typedef __bf16 bfx8 __attribute__((ext_vector_type(8)));
typedef unsigned short u16;
typedef unsigned int u32;

typedef __attribute__((address_space(1))) const void gas_t;
typedef __attribute__((address_space(3))) void las_t;

__device__ __forceinline__ u16 f2bf(float f) {
  u32 u = __float_as_uint(f);
  u = (u + 0x7fffu + ((u >> 16) & 1u)) >> 16;
  return (u16)u;
}

// HW packed f32->bf16 pair (T12): lo -> bits[15:0], hi -> bits[31:16]
__device__ __forceinline__ u32 cvtpk(float lo, float hi) {
  u32 r;
  asm("v_cvt_pk_bf16_f32 %0, %1, %2" : "=v"(r) : "v"(lo), "v"(hi));
  return r;
}

// async global->LDS, 16B per lane; lds arg must be wave-uniform base + lane*16
__device__ __forceinline__ void stage16(const void* g, void* l) {
  __builtin_amdgcn_global_load_lds((gas_t*)(uintptr_t)g, (las_t*)(uintptr_t)l,
                                   16, 0, 0);
}

// ---------------- fused fp32->bf16 convert: x | Wq | Wk | Wv | Wo ----------------
__global__ void k_cvtall(const float* __restrict__ x, const float* __restrict__ wq,
                         const float* __restrict__ wk, const float* __restrict__ wv,
                         const float* __restrict__ wo, u16* __restrict__ xbf,
                         u16* __restrict__ wout) {
  int i = (blockIdx.x * blockDim.x + threadIdx.x) * 4;
  const float* src;
  u16* dst;
  int off;
  if (i < 8388608) { src = x; dst = xbf; off = i; }
  else {
    int j = i - 8388608;
    if (j < 4194304) { src = wq; off = j; }
    else if (j < 6291456) { src = wk; off = j - 4194304; }
    else if (j < 8388608) { src = wv; off = j - 6291456; }
    else { src = wo; off = j - 8388608; }
    float4 v = *(const float4*)(src + off);
    u32 w0 = (u32)f2bf(v.x) | ((u32)f2bf(v.y) << 16);
    u32 w1 = (u32)f2bf(v.z) | ((u32)f2bf(v.w) << 16);
    *(uint2*)(wout + j) = make_uint2(w0, w1);
    return;
  }
  float4 v = *(const float4*)(src + off);
  u32 w0 = (u32)f2bf(v.x) | ((u32)f2bf(v.y) << 16);
  u32 w1 = (u32)f2bf(v.z) | ((u32)f2bf(v.w) << 16);
  *(uint2*)(dst + off) = make_uint2(w0, w1);
}

// ======== QKV GEMM: 128x256 tile, BK=32 dbuf, grid 512, XCD-chunked swizzle ========
__global__ __launch_bounds__(256, 2) void k_gemm256(const u16* __restrict__ A,
                                                    const u16* __restrict__ Bm,
                                                    u16* __restrict__ C,
                                                    int M, int N, int K) {
  __shared__ __align__(16) u16 As[2][128 * 32];
  __shared__ __align__(16) u16 Bs[2][256 * 32];
  const int nbn = N >> 8;
  const int bid = blockIdx.x;
  const int sw = ((bid & 7) << 6) | (bid >> 3);
  const int bm = sw / nbn, bn = sw % nbn;
  const int tid = threadIdx.x;
  const int w = tid >> 6, lane = tid & 63;
  const int lr = lane & 15, lg = lane >> 4;
  const int cw = (lg ^ ((lr >> 1) & 3)) * 8;
  const u16* Ab = A + (size_t)bm * 128 * K;
  const u16* Bb = Bm + (size_t)bn * 256 * K;
  const int NT = K >> 5;

  auto stage = [&](int buf, int tile) {
    u16* Ad = &As[buf][0];
    u16* Bd = &Bs[buf][0];
#pragma unroll
    for (int i = 0; i < 2; i++) {
      int q = tid + i * 256;
      int row = q >> 2, ch = q & 3;
      int sc = ch ^ ((row >> 1) & 3);
      stage16(Ab + (size_t)row * K + tile * 32 + sc * 8, Ad + q * 8);
    }
#pragma unroll
    for (int i = 0; i < 4; i++) {
      int q = tid + i * 256;
      int row = q >> 2, ch = q & 3;
      int sc = ch ^ ((row >> 1) & 3);
      stage16(Bb + (size_t)row * K + tile * 32 + sc * 8, Bd + q * 8);
    }
  };

  fx4 acc[8][4];
  const fx4 zero4 = {0.f, 0.f, 0.f, 0.f};
#pragma unroll
  for (int m = 0; m < 8; m++)
#pragma unroll
    for (int n = 0; n < 4; n++) acc[m][n] = zero4;

  stage(0, 0);
  asm volatile("s_waitcnt vmcnt(0)" ::: "memory");
  __builtin_amdgcn_s_barrier();

  const int arow = lr * 32;
  const int brow = (w * 64 + lr) * 32;
  bfx8 af[8], bf[4];

#pragma unroll 1
  for (int t = 0; t < NT; t++) {
    const int cur = t & 1;
    if (t + 1 < NT) {
      stage(cur ^ 1, t + 1);
      asm volatile("s_waitcnt vmcnt(6)" ::: "memory");
    } else {
      asm volatile("s_waitcnt vmcnt(0)" ::: "memory");  // tail drain (race fix)
    }
    __builtin_amdgcn_s_barrier();

    const u16* A0 = &As[cur][0];
    const u16* B0 = &Bs[cur][0];
#pragma unroll
    for (int mi = 0; mi < 8; mi++) af[mi] = *(const bfx8*)(A0 + arow + mi * 512 + cw);
#pragma unroll
    for (int n = 0; n < 4; n++) bf[n] = *(const bfx8*)(B0 + brow + n * 512 + cw);
    __builtin_amdgcn_s_setprio(1);
#pragma unroll
    for (int mi = 0; mi < 8; mi++)
#pragma unroll
      for (int n = 0; n < 4; n++)
        acc[mi][n] = __builtin_amdgcn_mfma_f32_16x16x32_bf16(af[mi], bf[n], acc[mi][n], 0, 0, 0);
    __builtin_amdgcn_s_setprio(0);
    __builtin_amdgcn_s_barrier();
  }

  const int r0 = bm * 128, c0 = bn * 256 + w * 64;
#pragma unroll
  for (int m = 0; m < 8; m++) {
#pragma unroll
    for (int n = 0; n < 4; n++) {
      int c = c0 + n * 16 + lr;
#pragma unroll
      for (int i = 0; i < 4; i++)
        C[(size_t)(r0 + m * 16 + lg * 4 + i) * N + c] = f2bf(acc[m][n][i]);
    }
  }
}

// ======== 128x128 GEMM, 2 merged phases/K-tile, f32+bias out, XCD swizzle ========
__global__ __launch_bounds__(256, 2) void k_gemmo(const u16* __restrict__ A,
                                                  const u16* __restrict__ Bm,
                                                  float* __restrict__ C,
                                                  const float* __restrict__ bias,
                                                  int M, int N, int K) {
  __shared__ __align__(16) u16 As[2][2][128 * 32];
  __shared__ __align__(16) u16 Bs[2][2][128 * 32];
  const int nbn = N >> 7;
  const int bid = blockIdx.x;
  const int sw = ((bid & 7) << 6) | (bid >> 3);  // 512 blocks, bijective
  const int bm = sw / nbn, bn = sw % nbn;
  const int tid = threadIdx.x;
  const int w = tid >> 6, lane = tid & 63;
  const int wm = w >> 1, wn = w & 1;
  const int lr = lane & 15, lg = lane >> 4;
  const int cw = (lg ^ ((lr >> 1) & 3)) * 8;
  const u16* Ab = A + (size_t)bm * 128 * K;
  const u16* Bb = Bm + (size_t)bn * 128 * K;
  const int NT = K >> 6;

  auto stage = [&](const u16* gb, u16* region, int tile, int kh) {
#pragma unroll
    for (int i = 0; i < 2; i++) {
      int q = tid + i * 256;
      int row = q >> 2, ch = q & 3;
      int sc = ch ^ ((row >> 1) & 3);
      stage16(gb + (size_t)row * K + tile * 64 + kh * 32 + sc * 8, region + q * 8);
    }
  };

  fx4 acc[4][4];
  const fx4 zero4 = {0.f, 0.f, 0.f, 0.f};
#pragma unroll
  for (int m = 0; m < 4; m++)
#pragma unroll
    for (int n = 0; n < 4; n++) acc[m][n] = zero4;

  stage(Ab, &As[0][0][0], 0, 0);
  stage(Bb, &Bs[0][0][0], 0, 0);
  stage(Ab, &As[0][1][0], 0, 1);
  stage(Bb, &Bs[0][1][0], 0, 1);
  stage(Ab, &As[1][0][0], 1, 0);
  stage(Bb, &Bs[1][0][0], 1, 0);
  asm volatile("s_waitcnt vmcnt(4)" ::: "memory");
  __builtin_amdgcn_s_barrier();

  const int arow = (wm * 64 + lr) * 32;
  const int brow = (wn * 64 + lr) * 32;
  bfx8 af[4], bf[4];

#pragma unroll 1
  for (int t = 0; t < NT; t++) {
    const u16* A0 = &As[t & 1][0][0];
    const u16* A1 = &As[t & 1][1][0];
    const u16* B0 = &Bs[t & 1][0][0];
    const u16* B1 = &Bs[t & 1][1][0];
    const int p1 = (t + 1) & 1, p2 = t & 1;

    // phase A: kh0
#pragma unroll
    for (int mi = 0; mi < 4; mi++) af[mi] = *(const bfx8*)(A0 + arow + mi * 512 + cw);
#pragma unroll
    for (int n = 0; n < 4; n++) bf[n] = *(const bfx8*)(B0 + brow + n * 512 + cw);
    if (t + 1 < NT) {
      stage(Ab, &As[p1][1][0], t + 1, 1);
      stage(Bb, &Bs[p1][1][0], t + 1, 1);
    }
    __builtin_amdgcn_s_barrier();
    __builtin_amdgcn_s_setprio(1);
#pragma unroll
    for (int mi = 0; mi < 4; mi++)
#pragma unroll
      for (int n = 0; n < 4; n++)
        acc[mi][n] = __builtin_amdgcn_mfma_f32_16x16x32_bf16(af[mi], bf[n], acc[mi][n], 0, 0, 0);
    __builtin_amdgcn_s_setprio(0);
    __builtin_amdgcn_s_barrier();

    // phase B: kh1
#pragma unroll
    for (int mi = 0; mi < 4; mi++) af[mi] = *(const bfx8*)(A1 + arow + mi * 512 + cw);
#pragma unroll
    for (int n = 0; n < 4; n++) bf[n] = *(const bfx8*)(B1 + brow + n * 512 + cw);
    if (t + 2 < NT) {
      stage(Ab, &As[p2][0][0], t + 2, 0);
      stage(Bb, &Bs[p2][0][0], t + 2, 0);
    }
    __builtin_amdgcn_s_barrier();
    __builtin_amdgcn_s_setprio(1);
#pragma unroll
    for (int mi = 0; mi < 4; mi++)
#pragma unroll
      for (int n = 0; n < 4; n++)
        acc[mi][n] = __builtin_amdgcn_mfma_f32_16x16x32_bf16(af[mi], bf[n], acc[mi][n], 0, 0, 0);
    __builtin_amdgcn_s_setprio(0);
    if (t + 2 < NT) {
      asm volatile("s_waitcnt vmcnt(4)" ::: "memory");
    } else {
      asm volatile("s_waitcnt vmcnt(0)" ::: "memory");  // tail drain (race fix)
    }
    __builtin_amdgcn_s_barrier();
  }

  const int r0 = bm * 128 + wm * 64, c0 = bn * 128 + wn * 64;
#pragma unroll
  for (int m = 0; m < 4; m++) {
#pragma unroll
    for (int n = 0; n < 4; n++) {
      int c = c0 + n * 16 + lr;
#pragma unroll
      for (int i = 0; i < 4; i++)
        C[(size_t)(r0 + m * 16 + lg * 4 + i) * N + c] = acc[m][n][i] + bias[c];
    }
  }
}

// ======== fused Q/K epilogue + V transpose: one launch, 2048 blocks ========
// blocks [0,1536): rmsnorm+rope relayout of Q/K (qkpost path).
// blocks [1536,2048): V transpose to vt[b][hkv][d][t] (vtr path).
__global__ __launch_bounds__(256) void k_post(const u16* __restrict__ qkv,
                                              const float* __restrict__ cosp,
                                              const float* __restrict__ sinp,
                                              const float* __restrict__ gq,
                                              const float* __restrict__ gk,
                                              u16* __restrict__ Qo,
                                              u16* __restrict__ Ko,
                                              u16* __restrict__ vt) {
  const int tid = threadIdx.x;
  if (blockIdx.x < 1536) {
    int bi = blockIdx.x;
    int hh = bi % 24;
    int t64 = (bi / 24) % 32;
    int b = bi / 768;
    int j = tid >> 2, p = tid & 3;
    int t = t64 * 64 + j;
    bool isq = hh < 16;
    int colbase = isq ? hh * 128 : 2048 + (hh - 16) * 128;
    const u16* src = qkv + ((size_t)(b * T_ + t)) * NQKV + colbase + p * 32;

    float xv[32];
#pragma unroll
    for (int c = 0; c < 4; c++) {
      uint4 raw = *(const uint4*)(src + c * 8);
      u32 wd[4] = {raw.x, raw.y, raw.z, raw.w};
#pragma unroll
      for (int q2 = 0; q2 < 4; q2++) {
        xv[c * 8 + q2 * 2 + 0] = __uint_as_float(wd[q2] << 16);
        xv[c * 8 + q2 * 2 + 1] = __uint_as_float(wd[q2] & 0xffff0000u);
      }
    }
    float ss = 0.f;
#pragma unroll
    for (int i = 0; i < 32; i++) ss += xv[i] * xv[i];
    ss += __shfl_xor(ss, 1);
    ss += __shfl_xor(ss, 2);
    float rinv = rsqrtf(ss * (1.0f / 128.0f) + 1e-6f);
    const float* g = isq ? gq : gk;
    const float* cr = cosp + (size_t)t * 128 + p * 32;
    const float* sr = sinp + (size_t)t * 128 + p * 32;

    float ov[32];
#pragma unroll
    for (int i = 0; i < 32; i++) {
      float y = xv[i] * rinv * g[p * 32 + i];
      float oth = __shfl_xor(y, 2);
      float rot = (p < 2) ? -oth : oth;
      ov[i] = y * cr[i] + rot * sr[i];
    }

    uint4 pk[4];
#pragma unroll
    for (int c = 0; c < 4; c++) {
      u32 wd[4];
#pragma unroll
      for (int q2 = 0; q2 < 4; q2++)
        wd[q2] = (u32)f2bf(ov[c * 8 + q2 * 2]) | ((u32)f2bf(ov[c * 8 + q2 * 2 + 1]) << 16);
      pk[c] = make_uint4(wd[0], wd[1], wd[2], wd[3]);
    }

    if (isq) {
      u16* dst = Qo + (((size_t)(b * NH + hh)) * T_ + t) * HD + p * 32;
#pragma unroll
      for (int c = 0; c < 4; c++) *(uint4*)(dst + c * 8) = pk[c];
    } else {
      int hk = hh - 16;
      u16* dstrow = Ko + (((size_t)(b * NKV + hk)) * T_ + t) * HD;
#pragma unroll
      for (int c = 0; c < 4; c++) {
        int C = p * 4 + c;
        int Cs = C ^ (t & 7);  // XOR swizzle, matches attn read
        *(uint4*)(dstrow + Cs * 8) = pk[c];
      }
    }
  } else {
    __shared__ __align__(16) u16 sm[128 * 64];
    int bi = blockIdx.x - 1536;
    int hv = bi & 7;
    int t64 = (bi >> 3) & 31;
    int b = bi >> 8;
#pragma unroll
    for (int it = 0; it < 4; it++) {
      int idx = tid + it * 256;
      int tok = idx >> 4, c = idx & 15;
      uint4 raw = *(const uint4*)(qkv + ((size_t)(b * T_ + t64 * 64 + tok)) * NQKV +
                                  3072 + hv * 128 + c * 8);
      u32 wd[4] = {raw.x, raw.y, raw.z, raw.w};
#pragma unroll
      for (int q2 = 0; q2 < 4; q2++) {
        sm[(c * 8 + q2 * 2 + 0) * 64 + tok] = (u16)(wd[q2] & 0xffffu);
        sm[(c * 8 + q2 * 2 + 1) * 64 + tok] = (u16)(wd[q2] >> 16);
      }
    }
    __syncthreads();
    int d = tid >> 1, half = tid & 1;
    size_t rowb = (((size_t)(b * NKV + hv)) * HD + d) * T_ + t64 * 64;
#pragma unroll
    for (int c = 0; c < 4; c++) {
      int cg = half * 4 + c;
      int cs = cg ^ (d & 7);
      u32 wd[4];
#pragma unroll
      for (int q2 = 0; q2 < 4; q2++) {
        u32 lo = sm[d * 64 + half * 32 + c * 8 + 2 * q2];
        u32 hi = sm[d * 64 + half * 32 + c * 8 + 2 * q2 + 1];
        wd[q2] = lo | (hi << 16);
      }
      *(uint4*)(vt + rowb + cs * 8) = make_uint4(wd[0], wd[1], wd[2], wd[3]);
    }
  }
}

// ---------------- flash attention v5 (r11 verbatim, PASSING ~72us) ----------
__global__ __launch_bounds__(512, 4) void k_attn(const u16* __restrict__ Qg,
                                                 const u16* __restrict__ Kg,
                                                 const u16* __restrict__ Vg,
                                                 u16* __restrict__ Og) {
  __shared__ __align__(16) u16 Ks[2][64 * 128];
  __shared__ __align__(16) u16 Vs[2][128 * 64];
  __shared__ __align__(16) u16 Ps[8][16 * 64];
  const int bi = blockIdx.x;
  const int zr = bi & 15, h = (bi >> 4) & 15, b = bi >> 8;
  const int z = b ? (15 - zr) : zr;
  const int hkv = h >> 1;
  const int tid = threadIdx.x, w = tid >> 6, lane = tid & 63;
  const int lr = lane & 15, lg = lane >> 4;
  const int zt = (w < 4) ? z : (31 - z);
  const int qr0 = zt * 64 + (w & 3) * 16;
  const int qrow = qr0 + lr;
  const int nch = 32 - z;
  const int myl = zt + 1;

  const u16* kb = Kg + ((size_t)(b * NKV + hkv)) * T_ * HD;
  const u16* vb = Vg + ((size_t)(b * NKV + hkv)) * HD * T_;
  u16* pw = &Ps[w][0];
  const fx4 zero4 = {0.f, 0.f, 0.f, 0.f};

  auto stageKV = [&](int buf, int kv0) {
    u16* Kd = &Ks[buf][0];
    u16* Vd = &Vs[buf][0];
#pragma unroll
    for (int it = 0; it < 2; it++) {
      int r = it * 32 + (tid >> 4);
      stage16(kb + (size_t)(kv0 + r) * HD + (tid & 15) * 8, Kd + it * 4096 + tid * 8);
      int d = it * 64 + (tid >> 3);
      stage16(vb + (size_t)d * T_ + kv0 + (tid & 7) * 8, Vd + it * 4096 + tid * 8);
    }
  };

  const u16* qbase = Qg + (((size_t)(b * NH + h)) * T_ + qrow) * HD;
  bfx8 qf[4];
#pragma unroll
  for (int kk = 0; kk < 4; kk++) qf[kk] = *(const bfx8*)(qbase + kk * 32 + lg * 8);

  fx4 o[8];
#pragma unroll
  for (int nf = 0; nf < 8; nf++) o[nf] = zero4;
  float l_i = 0.f;

  stageKV(0, 0);
  asm volatile("s_waitcnt vmcnt(0)" ::: "memory");
  __builtin_amdgcn_s_barrier();
  int cur = 0;

#pragma unroll 1
  for (int ch = 0; ch < nch; ch++) {
    if (ch + 1 < nch) {
      stageKV(cur ^ 1, (ch + 1) * 64);
      asm volatile("s_waitcnt vmcnt(4)" ::: "memory");
    } else {
      asm volatile("s_waitcnt vmcnt(0)" ::: "memory");
    }
    __builtin_amdgcn_s_barrier();

    if (ch < myl) {
      const u16* Kd = &Ks[cur][0];
      const u16* Vd = &Vs[cur][0];
      const int kv0 = ch * 64;
      const bool diag = (ch == zt);

      fx4 sa[4];
#pragma unroll
      for (int n = 0; n < 4; n++) sa[n] = zero4;
      __builtin_amdgcn_s_setprio(1);
#pragma unroll
      for (int n = 0; n < 4; n++) {
        const int kvl = n * 16 + lr;
        const u16* krow = Kd + kvl * 128;
#pragma unroll
        for (int kk = 0; kk < 4; kk++) {
          int cs = (kk * 4 + lg) ^ (kvl & 7);
          bfx8 kf = *(const bfx8*)(krow + cs * 8);
          sa[n] = __builtin_amdgcn_mfma_f32_16x16x32_bf16(kf, qf[kk], sa[n], 0, 0, 0);
        }
      }
      __builtin_amdgcn_s_setprio(0);

#pragma unroll
      for (int n = 0; n < 4; n++) {
        float p0 = exp2f(sa[n][0] * SC2_);
        float p1 = exp2f(sa[n][1] * SC2_);
        float p2 = exp2f(sa[n][2] * SC2_);
        float p3 = exp2f(sa[n][3] * SC2_);
        if (diag) {
          int kvg = kv0 + n * 16 + 4 * lg;
          p0 = (kvg + 0 > qrow) ? 0.f : p0;
          p1 = (kvg + 1 > qrow) ? 0.f : p1;
          p2 = (kvg + 2 > qrow) ? 0.f : p2;
          p3 = (kvg + 3 > qrow) ? 0.f : p3;
        }
        l_i += (p0 + p1) + (p2 + p3);
        u32 w0 = cvtpk(p0, p1);
        u32 w1 = cvtpk(p2, p3);
        int c = 2 * n + (lg >> 1);
        int cs = c ^ (lr & 7);
        *(uint2*)(pw + lr * 64 + cs * 8 + 4 * (lg & 1)) = make_uint2(w0, w1);
      }
      asm volatile("s_waitcnt lgkmcnt(0)" ::: "memory");
      __builtin_amdgcn_sched_barrier(0);

      bfx8 pa[2];
#pragma unroll
      for (int ks = 0; ks < 2; ks++) {
        int cp = (4 * ks + lg) ^ (lr & 7);
        pa[ks] = *(const bfx8*)(pw + lr * 64 + cp * 8);
      }
      __builtin_amdgcn_s_setprio(1);
#pragma unroll
      for (int nf = 0; nf < 8; nf++) {
        int d = nf * 16 + lr;
        const u16* vrow = Vd + d * 64;
#pragma unroll
        for (int ks = 0; ks < 2; ks++) {
          int cv = (4 * ks + lg) ^ (d & 7);
          bfx8 vf = *(const bfx8*)(vrow + cv * 8);
          o[nf] = __builtin_amdgcn_mfma_f32_16x16x32_bf16(pa[ks], vf, o[nf], 0, 0, 0);
        }
      }
      __builtin_amdgcn_s_setprio(0);
    }
    __builtin_amdgcn_s_barrier();
    cur ^= 1;
  }

  float lt = l_i + __shfl_xor(l_i, 16);
  lt += __shfl_xor(lt, 32);
  float inv[4];
#pragma unroll
  for (int i = 0; i < 4; i++) inv[i] = 1.0f / __shfl(lt, 4 * lg + i);
  u16* ob = Og + ((size_t)(b * T_ + qr0)) * DM + h * HD;
#pragma unroll
  for (int nf = 0; nf < 8; nf++)
#pragma unroll
    for (int i = 0; i < 4; i++)
      ob[(size_t)(4 * lg + i) * DM + nf * 16 + lr] = f2bf(o[nf][i] * inv[i]);
}

// ---------------- launch ----------------
extern "C" void kernel_launch(void* const* d_in, const int* in_sizes, int n_in,
                              void* d_out, int out_size, void* d_ws, size_t ws_size,
                              hipStream_t stream) {
  const float* x = (const float*)d_in[0];
  const float* cosp = (const float*)d_in[2];
  const float* sinp = (const float*)d_in[3];
  const float* Wq = (const float*)d_in[4];
  const float* Wk = (const float*)d_in[5];
  const float* Wv = (const float*)d_in[6];
  const float* Wo = (const float*)d_in[7];
  const float* bo = (const float*)d_in[8];
  const float* gq = (const float*)d_in[9];
  const float* gk = (const float*)d_in[10];

  char* ws = (char*)d_ws;
  u16* xbf  = (u16*)(ws + 0);           // 16 MB
  u16* wqkv = (u16*)(ws + 16777216);    // 16 MB (contiguous with wo below)
  u16* wo   = (u16*)(ws + 33554432);    // 8 MB
  u16* qkv  = (u16*)(ws + 41943040);    // 32 MB
  u16* qb   = (u16*)(ws + 75497472);    // 16 MB
  u16* kb   = (u16*)(ws + 92274688);    // 8 MB
  u16* vt   = (u16*)(ws + 100663296);   // 8 MB
  u16* ab   = (u16*)(ws + 109051904);   // 16 MB
  float* out = (float*)d_out;

  k_cvtall<<<20480, 256, 0, stream>>>(x, Wq, Wk, Wv, Wo, xbf, wqkv);

  k_gemm256<<<512, 256, 0, stream>>>(xbf, wqkv, qkv, 4096, 4096, 2048);
  k_post<<<2048, 256, 0, stream>>>(qkv, cosp, sinp, gq, gk, qb, kb, vt);
  k_attn<<<512, 512, 0, stream>>>(qb, kb, vt, ab);
  k_gemmo<<<512, 256, 0, stream>>>(ab, wo, out, bo, 4096, 2048, 2048);
}